// Round 5
// baseline (164.052 us; speedup 1.0000x reference)
//
#include <hip/hip_runtime.h>

// Problem constants
#define BATCH 8192
#define INF_  1024   // IN
#define OUTF  1024   // OUT
#define INV_B (1.0f/8192.0f)
#define RATE_C 1e-3f
#define SPLITZ 16    // GEMM2 split-K factor (bf16 partials)

typedef __bf16 bf16x8 __attribute__((ext_vector_type(8)));
typedef float  f32x4  __attribute__((ext_vector_type(4)));
typedef const __attribute__((address_space(1))) unsigned int* gas_t;
typedef __attribute__((address_space(3))) unsigned int* las_t;

// fp32 -> bf16 round-to-nearest-even
static __device__ __forceinline__ unsigned short f2bf(float f) {
  unsigned int u = __float_as_uint(f);
  u += 0x7fffu + ((u >> 16) & 1u);
  return (unsigned short)(u >> 16);
}
static __device__ __forceinline__ float bf2f(unsigned short h) {
  return __uint_as_float(((unsigned int)h) << 16);
}

// ---------------------------------------------------------------------------
// Kernel 1 (merged): blocks [0,2048): x -> xb (bf16) + xT (bf16, transposed)
//                    blocks [2048,3072): W row -> Wb + rate[o]
// ---------------------------------------------------------------------------
__global__ __launch_bounds__(256) void k_convert(
    const float* __restrict__ x, unsigned short* __restrict__ xb,
    unsigned short* __restrict__ xT, const float* __restrict__ W,
    unsigned short* __restrict__ Wb, float* __restrict__ rate) {
  const int t = threadIdx.x;
  if (blockIdx.x >= 2048) {
    __shared__ float red[256];
    const int o = blockIdx.x - 2048;
    float4 v = *(const float4*)&W[(size_t)o * INF_ + t * 4];
    ushort4 h;
    h.x = f2bf(v.x); h.y = f2bf(v.y); h.z = f2bf(v.z); h.w = f2bf(v.w);
    *(ushort4*)&Wb[(size_t)o * INF_ + t * 4] = h;
    red[t] = v.x * v.x + v.y * v.y + v.z * v.z + v.w * v.w;
    __syncthreads();
    for (int s = 128; s > 0; s >>= 1) {
      if (t < s) red[t] += red[t + s];
      __syncthreads();
    }
    if (t == 0) {
      float nrm = sqrtf(red[0]);
      rate[o] = RATE_C * sqrtf(fabsf(1.0f - nrm));
    }
    return;
  }
  // ---- x convert + transpose (64x64 tile), packed-u32 LDS ----
  __shared__ unsigned int t32[64][33];
  const int bx = blockIdx.x & 15;
  const int by = blockIdx.x >> 4;
  const int r0 = by * 64;
  const int c0 = bx * 64;
  const int m = t & 15;
  const int q = t >> 4;
#pragma unroll
  for (int p = 0; p < 2; ++p) {
    const int r2 = p * 16 + q;
    const int b  = r0 + 2 * r2;
    float4 v0 = *(const float4*)&x[(size_t)b * INF_ + c0 + 4 * m];
    float4 v1 = *(const float4*)&x[(size_t)(b + 1) * INF_ + c0 + 4 * m];
    ushort4 h0, h1;
    h0.x = f2bf(v0.x); h0.y = f2bf(v0.y); h0.z = f2bf(v0.z); h0.w = f2bf(v0.w);
    h1.x = f2bf(v1.x); h1.y = f2bf(v1.y); h1.z = f2bf(v1.z); h1.w = f2bf(v1.w);
    *(ushort4*)&xb[(size_t)b * INF_ + c0 + 4 * m] = h0;
    *(ushort4*)&xb[(size_t)(b + 1) * INF_ + c0 + 4 * m] = h1;
    t32[4 * m + 0][r2] = (unsigned int)h0.x | ((unsigned int)h1.x << 16);
    t32[4 * m + 1][r2] = (unsigned int)h0.y | ((unsigned int)h1.y << 16);
    t32[4 * m + 2][r2] = (unsigned int)h0.z | ((unsigned int)h1.z << 16);
    t32[4 * m + 3][r2] = (unsigned int)h0.w | ((unsigned int)h1.w << 16);
  }
  __syncthreads();
  const int c  = t >> 2;
  const int sg = t & 3;
  unsigned int vb[8];
#pragma unroll
  for (int k = 0; k < 8; ++k) vb[k] = t32[c][sg * 8 + k];
  unsigned short* dst = &xT[(size_t)(c0 + c) * BATCH + r0 + sg * 16];
  *(uint4*)&dst[0] = make_uint4(vb[0], vb[1], vb[2], vb[3]);
  *(uint4*)&dst[8] = make_uint4(vb[4], vb[5], vb[6], vb[7]);
}

// ---------------------------------------------------------------------------
// Kernel 2/4: NT bf16 GEMM, 128x128 tile, BK=64, global_load_lds width=16
// staging + XOR chunk swizzle. XCD-aware 1-D grids.
//   mode 0 (GEMM1, 512 blocks): bf16 C (= u) with bias.
//   mode 1 (GEMM2, 1024 blocks): bf16 partial K-slices.
// ---------------------------------------------------------------------------
__global__ __launch_bounds__(256, 3) void k_gemm(
    const unsigned short* __restrict__ A, const unsigned short* __restrict__ B,
    int lda, int ldb, int kChunk, void* __restrict__ C, int ldc,
    const float* __restrict__ bias, int mode) {
  __shared__ unsigned short As[128 * 64];
  __shared__ unsigned short Bs[128 * 64];
  const int t  = threadIdx.x;
  const int id = blockIdx.x;
  int bx, by, bz;
  if (mode == 0) {
    by = (id & 7) | ((id >> 6) << 3);
    bx = (id >> 3) & 7;
    bz = 0;
  } else {
    bz = ((id & 7) << 1) | ((id >> 3) & 1);
    by = (id >> 4) & 7;
    bx = id >> 7;
  }
  const int m0   = by * 128;
  const int n0   = bx * 128;
  const int k0   = bz * kChunk;
  const int lane = t & 63;
  const int wave = t >> 6;
  const int sr   = lane >> 3;
  const int scx  = ((lane & 7) ^ sr) * 8;
  const int wm   = (wave >> 1) * 64;
  const int wn   = (wave & 1) * 64;
  const int fm   = lane & 15;
  const int fk   = (lane >> 4) * 8;

  f32x4 acc[4][4] = {};

  const int ldsRow0 = wave * 8;
  const size_t gArow = (size_t)(m0 + ldsRow0 + sr) * lda + scx;
  const size_t gBrow = (size_t)(n0 + ldsRow0 + sr) * ldb + scx;

  for (int ks = 0; ks < kChunk; ks += 64) {
    const int k = k0 + ks;
#pragma unroll
    for (int j = 0; j < 4; ++j) {
      __builtin_amdgcn_global_load_lds(
          (gas_t)&A[gArow + (size_t)j * 32 * lda + k],
          (las_t)&As[(ldsRow0 + j * 32) * 64], 16, 0, 0);
      __builtin_amdgcn_global_load_lds(
          (gas_t)&B[gBrow + (size_t)j * 32 * ldb + k],
          (las_t)&Bs[(ldsRow0 + j * 32) * 64], 16, 0, 0);
    }
    __syncthreads();
#pragma unroll
    for (int kk = 0; kk < 64; kk += 32) {
      bf16x8 af[4], bf[4];
      const int swz = ((((kk + fk) >> 3) ^ (fm & 7)) << 3);
#pragma unroll
      for (int i = 0; i < 4; ++i)
        af[i] = *(const bf16x8*)&As[(wm + i * 16 + fm) * 64 + swz];
#pragma unroll
      for (int i = 0; i < 4; ++i)
        bf[i] = *(const bf16x8*)&Bs[(wn + i * 16 + fm) * 64 + swz];
#pragma unroll
      for (int mt = 0; mt < 4; ++mt)
#pragma unroll
        for (int nt = 0; nt < 4; ++nt)
          acc[mt][nt] = __builtin_amdgcn_mfma_f32_16x16x32_bf16(
              af[mt], bf[nt], acc[mt][nt], 0, 0, 0);
    }
    __syncthreads();
  }

  // Epilogue. C/D layout (m89): col = lane&15, row = (lane>>4)*4 + reg
  const int er = (lane >> 4) * 4;
  if (mode == 0) {
    unsigned short* Cb = (unsigned short*)C;
#pragma unroll
    for (int nt = 0; nt < 4; ++nt) {
      const int n  = n0 + wn + nt * 16 + fm;
      const float bv = bias[n];
#pragma unroll
      for (int mt = 0; mt < 4; ++mt) {
        const int mb = m0 + wm + mt * 16 + er;
#pragma unroll
        for (int r = 0; r < 4; ++r)
          Cb[(size_t)(mb + r) * ldc + n] = f2bf(acc[mt][nt][r] + bv);
      }
    }
  } else {
    unsigned short* Cp = (unsigned short*)C + (size_t)bz * (1024u * 1024u);
#pragma unroll
    for (int nt = 0; nt < 4; ++nt) {
      const int n = n0 + wn + nt * 16 + fm;
#pragma unroll
      for (int mt = 0; mt < 4; ++mt) {
        const int mb = m0 + wm + mt * 16 + er;
#pragma unroll
        for (int r = 0; r < 4; ++r)
          Cp[(size_t)(mb + r) * ldc + n] = f2bf(acc[mt][nt][r]);
      }
    }
  }
}

// ---------------------------------------------------------------------------
// Kernel 3 (fused row_stats + yn): 512 blocks x 16 batch rows, wave-per-row
// (4 rows per wave, sequential). Per row:
//   - read bf16 u row (lane covers cols lane*16..+15)
//   - max/argmax + sumexp via __shfl_xor butterflies
//   - exact argmax repair: candidates within 0.10 of approx max recomputed
//     in fp32 from x,W (covers bf16-storage err <=0.016 + GEMM err <=0.015)
//   - yn = +-exp(u-M)/se; sacc[o] += yn*u; pack bf16 into LDS tile
// LDS tile [16][1032] u16 with XOR chunk swizzle: 16B chunk c of a row sits
// at position c ^ ((c>>1)&7)  -> write = 2 b128/lane at uniform quad spread;
// transposed read ~2-way. Then transposed write to ynT + spart slab.
// ---------------------------------------------------------------------------
__global__ __launch_bounds__(256, 2) void k_softhebb(
    const unsigned short* __restrict__ ub, const float* __restrict__ x,
    const float* __restrict__ W, unsigned short* __restrict__ ynT,
    float* __restrict__ s_part) {
  __shared__ unsigned short tile[16][1032];
  __shared__ int cands[4][32];
  __shared__ int cnt[4];
  const int t     = threadIdx.x;
  const int lane  = t & 63;
  const int wave  = t >> 6;
  const int b0    = blockIdx.x * 16;
  const int oBase = lane * 16;

  float sacc[16];
#pragma unroll
  for (int j = 0; j < 16; ++j) sacc[j] = 0.0f;

  for (int rw = 0; rw < 4; ++rw) {
    const int r = wave * 4 + rw;
    const int b = b0 + r;
    // load u row (bf16 -> fp32)
    float a[16];
    {
      uint4 q0 = *(const uint4*)&ub[(size_t)b * OUTF + oBase];
      uint4 q1 = *(const uint4*)&ub[(size_t)b * OUTF + oBase + 8];
      const unsigned int* qa = (const unsigned int*)&q0;
      const unsigned int* qb = (const unsigned int*)&q1;
#pragma unroll
      for (int c = 0; c < 4; ++c) {
        a[2 * c]     = __uint_as_float(qa[c] << 16);
        a[2 * c + 1] = __uint_as_float(qa[c] & 0xffff0000u);
        a[8 + 2 * c]     = __uint_as_float(qb[c] << 16);
        a[8 + 2 * c + 1] = __uint_as_float(qb[c] & 0xffff0000u);
      }
    }
    // max / argmax (first-index-wins)
    float mv = a[0]; int mi = oBase;
#pragma unroll
    for (int j = 1; j < 16; ++j)
      if (a[j] > mv) { mv = a[j]; mi = oBase + j; }
#pragma unroll
    for (int off = 1; off < 64; off <<= 1) {
      float ov = __shfl_xor(mv, off);
      int   oi = __shfl_xor(mi, off);
      if (ov > mv || (ov == mv && oi < mi)) { mv = ov; mi = oi; }
    }
    const float M = mv;
    float se = 0.0f;
#pragma unroll
    for (int j = 0; j < 16; ++j) se += __expf(a[j] - M);
#pragma unroll
    for (int off = 1; off < 64; off <<= 1) se += __shfl_xor(se, off);

    // candidates within window
    const float thr = M - 0.10f;
    unsigned int cflags = 0;
    int ccount = 0;
#pragma unroll
    for (int j = 0; j < 16; ++j)
      if (a[j] >= thr) { cflags |= (1u << j); ++ccount; }
    int tot = ccount;
#pragma unroll
    for (int off = 1; off < 64; off <<= 1) tot += __shfl_xor(tot, off);

    int best = mi;
    if (tot > 1) {
      if (lane == 0) cnt[wave] = 0;
      for (int j = 0; j < 16; ++j)
        if (cflags & (1u << j)) {
          int p = atomicAdd(&cnt[wave], 1);
          if (p < 32) cands[wave][p] = oBase + j;
        }
      int nc = cnt[wave]; if (nc > 32) nc = 32;
      float xr[16];
      const float* xp = &x[(size_t)b * INF_ + oBase];
#pragma unroll
      for (int j = 0; j < 16; j += 4) {
        float4 v = *(const float4*)&xp[j];
        xr[j] = v.x; xr[j + 1] = v.y; xr[j + 2] = v.z; xr[j + 3] = v.w;
      }
      float bv = -3.4e38f; int bi = 0x7fffffff;
      for (int c = 0; c < nc; ++c) {
        const int o = cands[wave][c];
        const float* wp = &W[(size_t)o * INF_ + oBase];
        float d = 0.0f;
#pragma unroll
        for (int j = 0; j < 16; j += 4) {
          float4 v = *(const float4*)&wp[j];
          d += xr[j] * v.x + xr[j + 1] * v.y + xr[j + 2] * v.z +
               xr[j + 3] * v.w;
        }
#pragma unroll
        for (int off = 1; off < 64; off <<= 1) d += __shfl_xor(d, off);
        if (d > bv || (d == bv && o < bi)) { bv = d; bi = o; }
      }
      best = bi;
    }

    // yn + pack + LDS (swizzled)
    const float inv = 1.0f / se;
    uint4 pka, pkb;
    unsigned short* p0v = (unsigned short*)&pka;
    unsigned short* p1v = (unsigned short*)&pkb;
#pragma unroll
    for (int j = 0; j < 16; ++j) {
      float e  = __expf(a[j] - M) * inv;
      float yn = (oBase + j == best) ? e : -e;
      sacc[j] += yn * a[j];
      unsigned short hv = f2bf(yn);
      if (j < 8) p0v[j] = hv; else p1v[j - 8] = hv;
    }
    const int c0 = 2 * lane, c1 = 2 * lane + 1;
    const int sp0 = c0 ^ ((c0 >> 1) & 7);
    const int sp1 = c1 ^ ((c1 >> 1) & 7);
    *(uint4*)&tile[r][sp0 * 8] = pka;
    *(uint4*)&tile[r][sp1 * 8] = pkb;
  }

  // spart slab: row = blockIdx.x*4 + wave, coalesced fp32 stores
  {
    float* sp = &s_part[(size_t)(blockIdx.x * 4 + wave) * OUTF + oBase];
#pragma unroll
    for (int j = 0; j < 16; j += 4)
      *(float4*)&sp[j] = make_float4(sacc[j], sacc[j + 1], sacc[j + 2],
                                     sacc[j + 3]);
  }
  __syncthreads();

  // transposed writeout: thread covers o = t + 256*i
#pragma unroll
  for (int i = 0; i < 4; ++i) {
    const int o  = t + 256 * i;
    const int c  = o >> 3;
    const int sp = c ^ ((c >> 1) & 7);
    const int off = o & 7;
    uint4 v0, v1;
    unsigned short* va = (unsigned short*)&v0;
    unsigned short* vb = (unsigned short*)&v1;
#pragma unroll
    for (int r = 0; r < 8; ++r)  va[r] = tile[r][sp * 8 + off];
#pragma unroll
    for (int r = 0; r < 8; ++r)  vb[r] = tile[r + 8][sp * 8 + off];
    unsigned short* dst = &ynT[(size_t)o * BATCH + b0];
    *(uint4*)&dst[0] = v0;
    *(uint4*)&dst[8] = v1;
  }
}

// ---------------------------------------------------------------------------
// Kernel 5: block id -> o = (id&7)<<7 | id>>3  (XCD-local spart lines)
//   sb = (sum_k s_part[k][o]) / B
//   out[o][i] = rate[o] * (sum_z bf16 Cpart[z][o][i]/B - sb*W[o][i])
// ---------------------------------------------------------------------------
__global__ __launch_bounds__(256) void k_final(
    const unsigned short* __restrict__ Cp, const float* __restrict__ W,
    const float* __restrict__ s_part, const float* __restrict__ rate,
    float* __restrict__ out) {
  __shared__ float sred[256];
  const int t  = threadIdx.x;
  const int id = blockIdx.x;
  const int o  = ((id & 7) << 7) | (id >> 3);
  float sa = 0.0f;
  for (int k = t; k < 2048; k += 256) sa += s_part[(size_t)k * OUTF + o];
  sred[t] = sa;
  __syncthreads();
  for (int s2 = 128; s2 > 0; s2 >>= 1) {
    if (t < s2) sred[t] += sred[t + s2];
    __syncthreads();
  }
  const float sb = sred[0] * INV_B;
  const float rt = rate[o];
  const int i0 = t * 4;
  float cx = 0, cy = 0, cz = 0, cw = 0;
#pragma unroll
  for (int z = 0; z < SPLITZ; ++z) {
    ushort4 h = *(const ushort4*)&Cp[(size_t)z * (1024u * 1024u) +
                                     (size_t)o * INF_ + i0];
    cx += bf2f(h.x); cy += bf2f(h.y); cz += bf2f(h.z); cw += bf2f(h.w);
  }
  float4 w = *(const float4*)&W[(size_t)o * INF_ + i0];
  float4 r;
  r.x = rt * (cx * INV_B - sb * w.x);
  r.y = rt * (cy * INV_B - sb * w.y);
  r.z = rt * (cz * INV_B - sb * w.z);
  r.w = rt * (cw * INV_B - sb * w.w);
  *(float4*)&out[(size_t)o * INF_ + i0] = r;
}

// ---------------------------------------------------------------------------
// Workspace layout (bytes):
//   0        : ub bf16 [8192][1024] 16 MB (GEMM1 out; dead after k_softhebb)
//              REUSED (with xb) as GEMM2 bf16 Cpart[16][1024][1024] = 32 MB
//   16777216 : xb  bf16 16 MB (dead after GEMM1)
//   33554432 : xT  bf16 [1024][8192] 16 MB
//   50331648 : ynT bf16 [1024][8192] 16 MB
//   67108864 : Wb  bf16 2 MB
//   69206016 : rate fp32 [1024] 4 KB
//   69210112 : s_part fp32 [2048][1024] 8 MB
//   total ~77.6 MB
// ---------------------------------------------------------------------------
extern "C" void kernel_launch(void* const* d_in, const int* in_sizes, int n_in,
                              void* d_out, int out_size, void* d_ws, size_t ws_size,
                              hipStream_t stream) {
  const float* x    = (const float*)d_in[0];
  const float* W    = (const float*)d_in[1];
  const float* bias = (const float*)d_in[2];
  float* out = (float*)d_out;
  char* ws = (char*)d_ws;

  unsigned short* ub    = (unsigned short*)(ws + 0);
  unsigned short* xb    = (unsigned short*)(ws + 16777216);
  unsigned short* xT    = (unsigned short*)(ws + 33554432);
  unsigned short* ynT   = (unsigned short*)(ws + 50331648);
  unsigned short* Wb    = (unsigned short*)(ws + 67108864);
  float*          rate  = (float*)(ws + 69206016);
  float*          spart = (float*)(ws + 69210112);

  k_convert<<<dim3(3072), 256, 0, stream>>>(x, xb, xT, W, Wb, rate);
  // GEMM1: u[b][o] = x@W.T + b (bf16 out), M=8192 N=1024 K=1024, XCD-grouped
  k_gemm<<<dim3(512), 256, 0, stream>>>(xb, Wb, 1024, 1024, 1024,
                                        ub, 1024, bias, 0);
  // fused softmax-stats + exact-argmax repair + yn / ynT / spart
  k_softhebb<<<dim3(512), 256, 0, stream>>>(ub, x, W, ynT, spart);
  // GEMM2: C[o][i] = yn.T@x, M=1024 N=1024 K=8192, split-K x16 (bf16
  // partials overwrite ub+xb, both dead)
  k_gemm<<<dim3(1024), 256, 0, stream>>>(ynT, xT, 8192, 8192, 512,
                                         ws, 1024, nullptr, 1);
  k_final<<<dim3(1024), 256, 0, stream>>>((const unsigned short*)ws, W, spart,
                                          rate, out);
}